// Round 7
// baseline (182.466 us; speedup 1.0000x reference)
//
#include <hip/hip_runtime.h>
#include <hip/hip_bf16.h>

typedef _Float16 f16x8 __attribute__((ext_vector_type(8)));
typedef float f32x4 __attribute__((ext_vector_type(4)));

constexpr int B_ = 2, M_ = 5, C_ = 64, H_ = 128, W_ = 256;
constexpr int HW_ = H_ * W_;               // 32768
constexpr int PLANE_ = C_ * HW_;           // 2097152
constexpr int NIMG_ = B_ * M_;             // 10
constexpr int PH_ = H_ + 2, PW_ = W_ + 2;  // 130, 258

// workspace layout (bytes)
constexpr size_t OFF_XIN = 256;
constexpr size_t SZ_XIN  = (size_t)NIMG_ * PH_ * PW_ * 64 * 2;  // 42,931,200
constexpr size_t OFF_WL1 = OFF_XIN + SZ_XIN;
constexpr size_t SZ_WL   = (size_t)9 * 64 * 64 * 2;             // 73,728
constexpr size_t OFF_WL2 = OFF_WL1 + SZ_WL;
constexpr size_t OFF_N1  = OFF_WL2 + SZ_WL;
constexpr size_t SZ_N    = (size_t)NIMG_ * HW_ * 64 * 2;        // 41,943,040
constexpr size_t OFF_N2  = OFF_N1 + SZ_N;

// ---------------- dtype sniffer ----------------
__global__ void sniff_kernel(const unsigned short* __restrict__ pts,
                             int* __restrict__ flag) {
  int lane = threadIdx.x;  // block = 64
  unsigned short v = pts[2 * lane];
  int e = (v >> 7) & 0xFF;
  unsigned long long mask = __ballot(e >= 100 && e <= 140);
  if (lane == 0) flag[0] = (__popcll(mask) >= 48) ? 1 : 0;
}

// ---------------- zero the 1-px border of the padded NHWC buffer --------------
__global__ void border_zero(_Float16* __restrict__ x) {
  int idx = blockIdx.x * 256 + threadIdx.x;  // 10 * 772 = 7720 border pixels
  if (idx >= NIMG_ * 772) return;
  int img = idx / 772, r = idx - img * 772;
  int ph, pw;
  if (r < 258)      { ph = 0;            pw = r; }
  else if (r < 516) { ph = PH_ - 1;      pw = r - 258; }
  else if (r < 644) { ph = r - 516 + 1;  pw = 0; }
  else              { ph = r - 644 + 1;  pw = PW_ - 1; }
  f16x8 z = {};
  _Float16* p = x + ((size_t)(img * PH_ + ph) * PW_ + pw) * 64;
#pragma unroll
  for (int c8 = 0; c8 < 8; ++c8) *(f16x8*)(p + c8 * 8) = z;
}

// ---------------- NCHW (fp32|bf16) -> padded swizzled NHWC fp16 ---------------
__global__ __launch_bounds__(256) void prep_kernel(const void* __restrict__ in,
                                                   _Float16* __restrict__ xin,
                                                   const int* __restrict__ flag) {
  __shared__ float sT[64 * 65];
  const int t = threadIdx.x;
  const int wt = blockIdx.x, h = blockIdx.y, img = blockIdx.z;
  const bool isb = flag[0] != 0;
  const size_t ibase = (size_t)img * PLANE_ + (size_t)h * W_ + wt * 64;
#pragma unroll
  for (int k = 0; k < 16; ++k) {
    int idx = k * 256 + t;
    int ic = idx >> 6, w = idx & 63;
    size_t g = ibase + (size_t)ic * HW_ + w;
    float v = isb ? __bfloat162float(((const __hip_bfloat16*)in)[g])
                  : ((const float*)in)[g];
    sT[ic * 65 + w] = v;
  }
  __syncthreads();
#pragma unroll
  for (int k = 0; k < 2; ++k) {
    int idx = k * 256 + t;
    int w = idx >> 3, c8 = idx & 7;
    f16x8 vv;
#pragma unroll
    for (int j = 0; j < 8; ++j) vv[j] = (_Float16)sT[(c8 * 8 + j) * 65 + w];
    int pw = wt * 64 + w + 1;
    size_t rowbase = ((size_t)(img * PH_ + (h + 1)) * PW_ + pw) * 128;  // bytes
    int off = (c8 * 16) ^ ((pw & 7) << 4);
    *(f16x8*)((char*)xin + rowbase + off) = vv;
  }
}

// ---------------- W [oc][ic][3][3] -> swizzled fp16 [tap][oc][ic] -------------
__global__ void wprep_kernel(const void* __restrict__ W1, const void* __restrict__ W2,
                             _Float16* __restrict__ wl1, _Float16* __restrict__ wl2,
                             const int* __restrict__ flag) {
  int idx = blockIdx.x * 256 + threadIdx.x;  // 0..36863, grid.y selects matrix
  const bool isb = flag[0] != 0;
  const void* Wsrc = blockIdx.y ? W2 : W1;
  _Float16* dst = blockIdx.y ? wl2 : wl1;
  int tap = idx >> 12;            // /4096
  int oc = (idx >> 6) & 63;
  int ic = idx & 63;
  size_t s = (size_t)(oc * 64 + ic) * 9 + tap;
  float v = isb ? __bfloat162float(((const __hip_bfloat16*)Wsrc)[s])
                : ((const float*)Wsrc)[s];
  dst[(tap * 4096 + oc * 64 + ic) ^ ((oc & 7) << 3)] = (_Float16)v;
}

// ---------------- persistent fused conv: both convs, oc-half per block --------
// grid = 256 blocks x 512 threads (8 waves = 2/SIMD; 1 block/CU, reg cap 256).
// Block k: oc-half (k&1), tile set (k>>1)+128j, j=0..4. Wave = output row.
// conv1 B-frags (27 of 36) preloaded to registers once (weights tile-invariant)
// -> B LDS-reads per tile: 576 -> 360. Input staged via global_load_lds
// (zero staging VGPRs; xin pre-swizzled so linear DMA dest is correct).
__global__ __launch_bounds__(512, 2)
void conv_fused(const _Float16* __restrict__ xin,
                const _Float16* __restrict__ wl1, const _Float16* __restrict__ wl2,
                const void* __restrict__ bias1, const void* __restrict__ bias2,
                const int* __restrict__ flag,
                _Float16* __restrict__ n1, _Float16* __restrict__ n2) {
  __shared__ _Float16 sIn[10 * 66 * 64];    // 84,480 B, swizzled rows of 66 px
  __shared__ _Float16 sW[2 * 9 * 32 * 64];  // 73,728 B: [conv][tap][oc32][ic64]

  const int t = threadIdx.x;
  const int och = blockIdx.x & 1;
  const int pid = blockIdx.x >> 1;          // 0..127

  const int l = t & 63, wv = t >> 6;        // wv 0..7 = row
  const int lr = l & 15, hi = l >> 4;
  const bool isb = flag[0] != 0;

  // --- stage weights once (linear copy preserves pre-applied swizzle) ---
#pragma unroll
  for (int c = 0; c < 2; ++c) {
    const f16x8* src = (const f16x8*)((const char*)(c ? wl2 : wl1) + och * 4096);
    f16x8* dst = (f16x8*)sW + c * 2304;
    for (int i = t; i < 2304; i += 512) {
      int tap = i >> 8, e = i & 255;
      dst[i] = src[tap * 512 + e];   // src tap stride = 8192 B = 512 f16x8
    }
  }

  float bv1[2], bv2[2];
#pragma unroll
  for (int ob = 0; ob < 2; ++ob) {
    int oc = och * 32 + ob * 16 + lr;
    bv1[ob] = isb ? __bfloat162float(((const __hip_bfloat16*)bias1)[oc])
                  : ((const float*)bias1)[oc];
    bv2[ob] = isb ? __bfloat162float(((const __hip_bfloat16*)bias2)[oc])
                  : ((const float*)bias2)[oc];
  }

  // swizzled channel-offset terms
  int c2a[3][2], c2b[2];
#pragma unroll
  for (int dx = 0; dx < 3; ++dx) {
    int key = (((l & 7) + dx) & 7) << 4;
#pragma unroll
    for (int kw = 0; kw < 2; ++kw) c2a[dx][kw] = (hi * 16 + kw * 64) ^ key;
  }
#pragma unroll
  for (int kw = 0; kw < 2; ++kw) c2b[kw] = (hi * 16 + kw * 64) ^ ((l & 7) << 4);

  const char* sInB = (const char*)sIn;
  const char* sWB = (const char*)sW;

  __syncthreads();  // weights visible before register preload

  // --- preload conv1 B-frags: all (tap,kw) for ob=0, plus kw=0 for ob=1 ---
  // 27 frags = 108 VGPRs. Remaining conv1 (tap,kw=1,ob=1) + all conv2 from LDS.
  f16x8 b1r0[9][2];  // [tap][kw], ob = 0
  f16x8 b1r1[9];     // [tap],    ob = 1, kw = 0
#pragma unroll
  for (int tap = 0; tap < 9; ++tap) {
#pragma unroll
    for (int kw = 0; kw < 2; ++kw)
      b1r0[tap][kw] = *(const f16x8*)(sWB + tap * 4096 + lr * 128 + c2b[kw]);
    b1r1[tap] = *(const f16x8*)(sWB + tap * 4096 + (16 + lr) * 128 + c2b[0]);
  }

  // --- async staging: global_load_lds, 16 B per lane, linear dest ---
  auto stage = [&](int tt) {
    int img = tt >> 6, hy = (tt >> 2) & 15, wx = tt & 3;
    const _Float16* tb = xin + ((size_t)(img * PH_ + hy * 8) * PW_ + wx * 64) * 64;
#pragma unroll
    for (int u = 0; u < 11; ++u) {
      int c = u * 512 + t;  // chunk id, 16 B each; 5280 total
      if (u < 10 || c < 5280) {
        int r = c / 528, cc = c - r * 528;
        const _Float16* g = tb + (size_t)r * (PW_ * 64) + cc * 8;
        __builtin_amdgcn_global_load_lds(
            (const __attribute__((address_space(1))) void*)g,
            (__attribute__((address_space(3))) void*)(sIn + c * 8), 16, 0, 0);
      }
    }
  };

#pragma unroll 1
  for (int j = 0; j < 5; ++j) {
    const int tt = pid + 128 * j;

    stage(tt);
    asm volatile("s_waitcnt vmcnt(0)" ::: "memory");
    __syncthreads();  // all waves' DMA landed

    f32x4 acc1[4][2], acc2[4][2];
#pragma unroll
    for (int pa = 0; pa < 4; ++pa)
#pragma unroll
      for (int ob = 0; ob < 2; ++ob) {
        acc1[pa][ob] = (f32x4){bv1[ob], bv1[ob], bv1[ob], bv1[ob]};
        acc2[pa][ob] = (f32x4){bv2[ob], bv2[ob], bv2[ob], bv2[ob]};
      }

#pragma unroll
    for (int ky = 0; ky < 3; ++ky) {
#pragma unroll
      for (int kx = 0; kx < 3; ++kx) {
        const int tap = ky * 3 + kx;
#pragma unroll
        for (int kw = 0; kw < 2; ++kw) {
          f16x8 a[4];
#pragma unroll
          for (int pa = 0; pa < 4; ++pa)
            a[pa] = *(const f16x8*)(sInB + ((wv + ky) * 8448 + (pa * 16 + lr + kx) * 128 + c2a[kx][kw]));
          // conv1 B: regs where preloaded, LDS for (kw=1, ob=1)
          f16x8 b1a = b1r0[tap][kw];
          f16x8 b1b = (kw == 0) ? b1r1[tap]
                                : *(const f16x8*)(sWB + tap * 4096 + (16 + lr) * 128 + c2b[1]);
          f16x8 b2a = *(const f16x8*)(sWB + 36864 + tap * 4096 + lr * 128 + c2b[kw]);
          f16x8 b2b = *(const f16x8*)(sWB + 36864 + tap * 4096 + (16 + lr) * 128 + c2b[kw]);
#pragma unroll
          for (int pa = 0; pa < 4; ++pa) {
            acc1[pa][0] = __builtin_amdgcn_mfma_f32_16x16x32_f16(a[pa], b1a, acc1[pa][0], 0, 0, 0);
            acc1[pa][1] = __builtin_amdgcn_mfma_f32_16x16x32_f16(a[pa], b1b, acc1[pa][1], 0, 0, 0);
            acc2[pa][0] = __builtin_amdgcn_mfma_f32_16x16x32_f16(a[pa], b2a, acc2[pa][0], 0, 0, 0);
            acc2[pa][1] = __builtin_amdgcn_mfma_f32_16x16x32_f16(a[pa], b2b, acc2[pa][1], 0, 0, 0);
          }
        }
      }
    }

    // epilogue: tanh(3x) = 1 - 2*rcp(1+exp2(8.656*u)); no clamp needed
    {
      int img = tt >> 6, hy = (tt >> 2) & 15, wx = tt & 3;
      size_t rowbase = ((size_t)(img * H_ + hy * 8 + wv) * W_ + wx * 64) * 64 + och * 32 + lr;
#pragma unroll
      for (int pa = 0; pa < 4; ++pa)
#pragma unroll
        for (int ob = 0; ob < 2; ++ob)
#pragma unroll
          for (int r = 0; r < 4; ++r) {
            int px = pa * 16 + hi * 4 + r;
            size_t o = rowbase + (size_t)px * 64 + ob * 16;
            float e1 = __builtin_exp2f(acc1[pa][ob][r] * 8.656170245f);
            n1[o] = (_Float16)fmaf(-2.f, __builtin_amdgcn_rcpf(1.f + e1), 1.f);
            float e2 = __builtin_exp2f(acc2[pa][ob][r] * 8.656170245f);
            n2[o] = (_Float16)fmaf(-2.f, __builtin_amdgcn_rcpf(1.f + e2), 1.f);
          }
    }
    __syncthreads();  // all waves done reading sIn before next DMA overwrites
  }
}

// ---------------- gram + antisym + sigmoid + eye + row-normalize --------------
// 8 lanes cooperate per pixel: lane octet j owns channels 8j..8j+7.
__global__ __launch_bounds__(256)
void pairwise_kernel(const _Float16* __restrict__ n1, const _Float16* __restrict__ n2,
                     void* __restrict__ out, const int* __restrict__ flag) {
  int tid = blockIdx.x * 256 + threadIdx.x;
  int gp = tid >> 3;               // pixel id 0 .. B*HW-1
  int j = tid & 7;                 // channel octet
  int b = gp >> 15, px = gp & (HW_ - 1);
  const _Float16* p1 = n1 + ((size_t)(b * M_) * HW_ + px) * 64 + j * 8;
  const _Float16* p2 = n2 + ((size_t)(b * M_) * HW_ + px) * 64 + j * 8;

  f16x8 A[M_], Bv[M_];
#pragma unroll
  for (int m = 0; m < M_; ++m) {
    A[m]  = *(const f16x8*)(p1 + (size_t)m * PLANE_);
    Bv[m] = *(const f16x8*)(p2 + (size_t)m * PLANE_);
  }

  float s[M_][M_];
#pragma unroll
  for (int m = 0; m < M_; ++m)
#pragma unroll
    for (int n = 0; n < M_; ++n) s[m][n] = 0.f;

#pragma unroll
  for (int jj = 0; jj < 8; ++jj)
#pragma unroll
    for (int m = 0; m < M_; ++m)
#pragma unroll
      for (int n = 0; n < M_; ++n)
        s[m][n] += (float)A[m][jj] * (float)Bv[n][jj];

#pragma unroll
  for (int m = 0; m < M_; ++m)
#pragma unroll
    for (int n = 0; n < M_; ++n) {
      s[m][n] += __shfl_xor(s[m][n], 1);
      s[m][n] += __shfl_xor(s[m][n], 2);
      s[m][n] += __shfl_xor(s[m][n], 4);
    }

  float adj[M_][M_], rs[M_];
#pragma unroll
  for (int m = 0; m < M_; ++m) {
    float r = 0.f;
#pragma unroll
    for (int n = 0; n < M_; ++n) {
      float a = s[m][n] - s[n][m];
      float e = __builtin_exp2f(a * -4.328085123f);  // exp(-3a)
      float v = __builtin_amdgcn_rcpf(1.f + e);
      if (m == n) v += 1.f;
      adj[m][n] = v;
      r += v;
    }
    rs[m] = r;
  }

  const bool isb = flag[0] != 0;
  for (int k = j; k < 25; k += 8) {
    int m = k / 5, n = k - m * 5;
    float v = adj[m][n] * __builtin_amdgcn_rcpf(rs[m]);
    size_t o = ((size_t)((b * M_ + m) * M_ + n)) * HW_ + px;
    if (isb) ((__hip_bfloat16*)out)[o] = __float2bfloat16(v);
    else     ((float*)out)[o] = v;
  }
}

// ---------------- launch ----------------
extern "C" void kernel_launch(void* const* d_in, const int* in_sizes, int n_in,
                              void* d_out, int out_size, void* d_ws, size_t ws_size,
                              hipStream_t stream) {
  const void* pts = d_in[0];
  const void* W1  = d_in[1];
  const void* b1  = d_in[2];
  const void* W2  = d_in[3];
  const void* b2  = d_in[4];

  char* ws = (char*)d_ws;
  int* flag = (int*)ws;
  _Float16* xin = (_Float16*)(ws + OFF_XIN);
  _Float16* wl1 = (_Float16*)(ws + OFF_WL1);
  _Float16* wl2 = (_Float16*)(ws + OFF_WL2);
  _Float16* n1  = (_Float16*)(ws + OFF_N1);
  _Float16* n2  = (_Float16*)(ws + OFF_N2);

  sniff_kernel<<<dim3(1), dim3(64), 0, stream>>>((const unsigned short*)pts, flag);
  border_zero<<<dim3((NIMG_ * 772 + 255) / 256), dim3(256), 0, stream>>>(xin);
  prep_kernel<<<dim3(4, H_, NIMG_), dim3(256), 0, stream>>>(pts, xin, flag);
  wprep_kernel<<<dim3(144, 2), dim3(256), 0, stream>>>(W1, W2, wl1, wl2, flag);
  conv_fused<<<dim3(256), dim3(512), 0, stream>>>(xin, wl1, wl2, b1, b2, flag, n1, n2);
  pairwise_kernel<<<dim3(B_ * HW_ * 8 / 256), dim3(256), 0, stream>>>(n1, n2, d_out, flag);
}

// Round 8
// 130.294 us; speedup vs baseline: 1.4004x; 1.4004x over previous
//
#include <hip/hip_runtime.h>
#include <hip/hip_bf16.h>

typedef _Float16 f16x8 __attribute__((ext_vector_type(8)));
typedef float f32x4 __attribute__((ext_vector_type(4)));

constexpr int B_ = 2, M_ = 5, C_ = 64, H_ = 128, W_ = 256;
constexpr int HW_ = H_ * W_;               // 32768
constexpr int PLANE_ = C_ * HW_;           // 2097152
constexpr int NIMG_ = B_ * M_;             // 10
constexpr int PH_ = H_ + 2, PW_ = W_ + 2;  // 130, 258

// workspace layout (bytes)
constexpr size_t OFF_XIN = 256;
constexpr size_t SZ_XIN  = (size_t)NIMG_ * PH_ * PW_ * 64 * 2;  // 42,931,200
constexpr size_t OFF_WL1 = OFF_XIN + SZ_XIN;
constexpr size_t SZ_WL   = (size_t)9 * 64 * 64 * 2;             // 73,728
constexpr size_t OFF_WL2 = OFF_WL1 + SZ_WL;
constexpr size_t OFF_N1  = OFF_WL2 + SZ_WL;
constexpr size_t SZ_N    = (size_t)NIMG_ * HW_ * 64 * 2;        // 41,943,040
constexpr size_t OFF_N2  = OFF_N1 + SZ_N;

// ---------------- dtype sniffer ----------------
__global__ void sniff_kernel(const unsigned short* __restrict__ pts,
                             int* __restrict__ flag) {
  int lane = threadIdx.x;  // block = 64
  unsigned short v = pts[2 * lane];
  int e = (v >> 7) & 0xFF;
  unsigned long long mask = __ballot(e >= 100 && e <= 140);
  if (lane == 0) flag[0] = (__popcll(mask) >= 48) ? 1 : 0;
}

// ---------------- NCHW (fp32|bf16) -> padded swizzled NHWC fp16 ---------------
__global__ __launch_bounds__(256) void prep_kernel(const void* __restrict__ in,
                                                   _Float16* __restrict__ xin,
                                                   const int* __restrict__ flag) {
  __shared__ float sT[64 * 65];
  const int t = threadIdx.x;
  const int wt = blockIdx.x, h = blockIdx.y, img = blockIdx.z;
  const bool isb = flag[0] != 0;
  const size_t ibase = (size_t)img * PLANE_ + (size_t)h * W_ + wt * 64;
#pragma unroll
  for (int k = 0; k < 16; ++k) {
    int idx = k * 256 + t;
    int ic = idx >> 6, w = idx & 63;
    size_t g = ibase + (size_t)ic * HW_ + w;
    float v = isb ? __bfloat162float(((const __hip_bfloat16*)in)[g])
                  : ((const float*)in)[g];
    sT[ic * 65 + w] = v;
  }
  __syncthreads();
#pragma unroll
  for (int k = 0; k < 2; ++k) {
    int idx = k * 256 + t;
    int w = idx >> 3, c8 = idx & 7;
    f16x8 vv;
#pragma unroll
    for (int j = 0; j < 8; ++j) vv[j] = (_Float16)sT[(c8 * 8 + j) * 65 + w];
    int pw = wt * 64 + w + 1;
    size_t rowbase = ((size_t)(img * PH_ + (h + 1)) * PW_ + pw) * 128;  // bytes
    int off = (c8 * 16) ^ ((pw & 7) << 4);
    *(f16x8*)((char*)xin + rowbase + off) = vv;
  }
}

// ------- W [oc][ic][3][3] -> swizzled fp16 [tap][oc][ic]; + border zeroing ----
__global__ void wprep_kernel(const void* __restrict__ W1, const void* __restrict__ W2,
                             _Float16* __restrict__ wl1, _Float16* __restrict__ wl2,
                             _Float16* __restrict__ xin,
                             const int* __restrict__ flag) {
  const int t = threadIdx.x;
  if (blockIdx.x >= 144) {
    // border zeroing of padded NHWC buffer (only on y==0 copy)
    if (blockIdx.y != 0) return;
    int idx = (blockIdx.x - 144) * 256 + t;  // 7720 border pixels
    if (idx >= NIMG_ * 772) return;
    int img = idx / 772, r = idx - img * 772;
    int ph, pw;
    if (r < 258)      { ph = 0;            pw = r; }
    else if (r < 516) { ph = PH_ - 1;      pw = r - 258; }
    else if (r < 644) { ph = r - 516 + 1;  pw = 0; }
    else              { ph = r - 644 + 1;  pw = PW_ - 1; }
    f16x8 z = {};
    _Float16* p = xin + ((size_t)(img * PH_ + ph) * PW_ + pw) * 64;
#pragma unroll
    for (int c8 = 0; c8 < 8; ++c8) *(f16x8*)(p + c8 * 8) = z;
    return;
  }
  int idx = blockIdx.x * 256 + t;  // 0..36863, grid.y selects matrix
  const bool isb = flag[0] != 0;
  const void* Wsrc = blockIdx.y ? W2 : W1;
  _Float16* dst = blockIdx.y ? wl2 : wl1;
  int tap = idx >> 12;            // /4096
  int oc = (idx >> 6) & 63;
  int ic = idx & 63;
  size_t s = (size_t)(oc * 64 + ic) * 9 + tap;
  float v = isb ? __bfloat162float(((const __hip_bfloat16*)Wsrc)[s])
                : ((const float*)Wsrc)[s];
  dst[(tap * 4096 + oc * 64 + ic) ^ ((oc & 7) << 3)] = (_Float16)v;
}

// ---------------- persistent fused conv: both convs, oc-half per block --------
// grid = 256 blocks x 512 threads (8 waves; 1 block/CU; reg cap 256 -> no spill).
// Block k: oc-half (k&1), tile set (k>>1)+128j, j=0..4. Wave = output row.
// Barrier discipline (m201 pattern): ready-barrier = lgkmcnt(0)+s_barrier only
// (T14 prefetch global loads stay in flight across it); release-barrier = bare
// s_barrier (ds_reads already retired via MFMA data deps). Epilogue after the
// release barrier so stores overlap next tile's ds_write.
__global__ __launch_bounds__(512, 2)
void conv_fused(const _Float16* __restrict__ xin,
                const _Float16* __restrict__ wl1, const _Float16* __restrict__ wl2,
                const void* __restrict__ bias1, const void* __restrict__ bias2,
                const int* __restrict__ flag,
                _Float16* __restrict__ n1, _Float16* __restrict__ n2) {
  __shared__ _Float16 sIn[10 * 66 * 64];    // 84,480 B, swizzled rows of 66 px
  __shared__ _Float16 sW[2 * 9 * 32 * 64];  // 73,728 B: [conv][tap][oc32][ic64]

  const int t = threadIdx.x;
  const int och = blockIdx.x & 1;
  const int pid = blockIdx.x >> 1;          // 0..127

  const int l = t & 63, wv = t >> 6;        // wv 0..7 = row
  const int lr = l & 15, hi = l >> 4;
  const bool isb = flag[0] != 0;

  // --- stage weights once (linear copy preserves pre-applied swizzle) ---
#pragma unroll
  for (int c = 0; c < 2; ++c) {
    const f16x8* src = (const f16x8*)((const char*)(c ? wl2 : wl1) + och * 4096);
    f16x8* dst = (f16x8*)sW + c * 2304;
    for (int i = t; i < 2304; i += 512) {
      int tap = i >> 8, e = i & 255;
      dst[i] = src[tap * 512 + e];   // src tap stride = 8192 B = 512 f16x8
    }
  }

  float bv1[2], bv2[2];
#pragma unroll
  for (int ob = 0; ob < 2; ++ob) {
    int oc = och * 32 + ob * 16 + lr;
    bv1[ob] = isb ? __bfloat162float(((const __hip_bfloat16*)bias1)[oc])
                  : ((const float*)bias1)[oc];
    bv2[ob] = isb ? __bfloat162float(((const __hip_bfloat16*)bias2)[oc])
                  : ((const float*)bias2)[oc];
  }

  // swizzled channel-offset terms
  int c2a[3][2], c2b[2];
#pragma unroll
  for (int dx = 0; dx < 3; ++dx) {
    int key = (((l & 7) + dx) & 7) << 4;
#pragma unroll
    for (int kw = 0; kw < 2; ++kw) c2a[dx][kw] = (hi * 16 + kw * 64) ^ key;
  }
#pragma unroll
  for (int kw = 0; kw < 2; ++kw) c2b[kw] = (hi * 16 + kw * 64) ^ ((l & 7) << 4);

  // --- register staging: tile = 5280 f16x8; 11 regs/thread (512 thr) ---
  f16x8 rg[11];
  auto issue = [&](int tt) {
    int img = tt >> 6, hy = (tt >> 2) & 15, wx = tt & 3;
    const f16x8* base = (const f16x8*)(xin + ((size_t)(img * PH_ + hy * 8) * PW_ + wx * 64) * 64);
#pragma unroll
    for (int u = 0; u < 11; ++u) {
      int i = u * 512 + t;
      if (u < 10 || i < 5280) {
        int r = i / 528, cc = i - r * 528;
        rg[u] = base[(size_t)r * (PW_ * 8) + cc];  // row stride = PW_*8 f16x8
      }
    }
  };

  issue(pid);  // tile for j=0

  const char* sInB = (const char*)sIn;
  const char* sWB = (const char*)sW;

  __syncthreads();  // weights staged before first compute (full drain once, ok)

#pragma unroll 1
  for (int j = 0; j < 5; ++j) {
    const int tt = pid + 128 * j;

    // ds_write staged tile (sIn f16x8-linear == staging index);
    // compiler inserts the vmcnt wait for rg deps automatically.
#pragma unroll
    for (int u = 0; u < 11; ++u) {
      int i = u * 512 + t;
      if (u < 10 || i < 5280) ((f16x8*)sIn)[i] = rg[u];
    }
    // ready-barrier: only LDS writes must be visible; leave vmcnt in flight
    asm volatile("s_waitcnt lgkmcnt(0)" ::: "memory");
    __builtin_amdgcn_s_barrier();

    if (j < 4) issue(pid + 128 * (j + 1));  // T14: next tile in flight

    f32x4 acc1[4][2], acc2[4][2];
#pragma unroll
    for (int pa = 0; pa < 4; ++pa)
#pragma unroll
      for (int ob = 0; ob < 2; ++ob) {
        acc1[pa][ob] = (f32x4){bv1[ob], bv1[ob], bv1[ob], bv1[ob]};
        acc2[pa][ob] = (f32x4){bv2[ob], bv2[ob], bv2[ob], bv2[ob]};
      }

    __builtin_amdgcn_s_setprio(1);
#pragma unroll
    for (int ky = 0; ky < 3; ++ky) {
#pragma unroll
      for (int kx = 0; kx < 3; ++kx) {
        const int tap = ky * 3 + kx;
#pragma unroll
        for (int kw = 0; kw < 2; ++kw) {
          f16x8 a[4], b1a, b1b, b2a, b2b;
#pragma unroll
          for (int pa = 0; pa < 4; ++pa)
            a[pa] = *(const f16x8*)(sInB + ((wv + ky) * 8448 + (pa * 16 + lr + kx) * 128 + c2a[kx][kw]));
          b1a = *(const f16x8*)(sWB + tap * 4096 + lr * 128 + c2b[kw]);
          b1b = *(const f16x8*)(sWB + tap * 4096 + (16 + lr) * 128 + c2b[kw]);
          b2a = *(const f16x8*)(sWB + 36864 + tap * 4096 + lr * 128 + c2b[kw]);
          b2b = *(const f16x8*)(sWB + 36864 + tap * 4096 + (16 + lr) * 128 + c2b[kw]);
#pragma unroll
          for (int pa = 0; pa < 4; ++pa) {
            acc1[pa][0] = __builtin_amdgcn_mfma_f32_16x16x32_f16(a[pa], b1a, acc1[pa][0], 0, 0, 0);
            acc1[pa][1] = __builtin_amdgcn_mfma_f32_16x16x32_f16(a[pa], b1b, acc1[pa][1], 0, 0, 0);
            acc2[pa][0] = __builtin_amdgcn_mfma_f32_16x16x32_f16(a[pa], b2a, acc2[pa][0], 0, 0, 0);
            acc2[pa][1] = __builtin_amdgcn_mfma_f32_16x16x32_f16(a[pa], b2b, acc2[pa][1], 0, 0, 0);
          }
        }
      }
    }
    __builtin_amdgcn_s_setprio(0);

    // release-barrier: ds_reads already retired via MFMA data deps
    __builtin_amdgcn_s_barrier();

    // epilogue after the barrier: overlaps next iteration's ds_write.
    // tanh(3x) = 1 - 2*rcp(1+exp2(8.656*u)); no clamp needed
    {
      int img = tt >> 6, hy = (tt >> 2) & 15, wx = tt & 3;
      size_t rowbase = ((size_t)(img * H_ + hy * 8 + wv) * W_ + wx * 64) * 64
                       + och * 32 + lr;
#pragma unroll
      for (int pa = 0; pa < 4; ++pa)
#pragma unroll
        for (int ob = 0; ob < 2; ++ob)
#pragma unroll
          for (int r = 0; r < 4; ++r) {
            int px = pa * 16 + hi * 4 + r;
            size_t o = rowbase + (size_t)px * 64 + ob * 16;
            float e1 = __builtin_exp2f(acc1[pa][ob][r] * 8.656170245f);
            n1[o] = (_Float16)fmaf(-2.f, __builtin_amdgcn_rcpf(1.f + e1), 1.f);
            float e2 = __builtin_exp2f(acc2[pa][ob][r] * 8.656170245f);
            n2[o] = (_Float16)fmaf(-2.f, __builtin_amdgcn_rcpf(1.f + e2), 1.f);
          }
    }
  }
}

// ---------------- gram + antisym + sigmoid + eye + row-normalize --------------
// 8 lanes cooperate per pixel: lane octet j owns channels 8j..8j+7.
__global__ __launch_bounds__(256)
void pairwise_kernel(const _Float16* __restrict__ n1, const _Float16* __restrict__ n2,
                     void* __restrict__ out, const int* __restrict__ flag) {
  int tid = blockIdx.x * 256 + threadIdx.x;
  int gp = tid >> 3;               // pixel id 0 .. B*HW-1
  int j = tid & 7;                 // channel octet
  int b = gp >> 15, px = gp & (HW_ - 1);
  const _Float16* p1 = n1 + ((size_t)(b * M_) * HW_ + px) * 64 + j * 8;
  const _Float16* p2 = n2 + ((size_t)(b * M_) * HW_ + px) * 64 + j * 8;

  f16x8 A[M_], Bv[M_];
#pragma unroll
  for (int m = 0; m < M_; ++m) {
    A[m]  = *(const f16x8*)(p1 + (size_t)m * PLANE_);
    Bv[m] = *(const f16x8*)(p2 + (size_t)m * PLANE_);
  }

  float s[M_][M_];
#pragma unroll
  for (int m = 0; m < M_; ++m)
#pragma unroll
    for (int n = 0; n < M_; ++n) s[m][n] = 0.f;

#pragma unroll
  for (int jj = 0; jj < 8; ++jj)
#pragma unroll
    for (int m = 0; m < M_; ++m)
#pragma unroll
      for (int n = 0; n < M_; ++n)
        s[m][n] += (float)A[m][jj] * (float)Bv[n][jj];

#pragma unroll
  for (int m = 0; m < M_; ++m)
#pragma unroll
    for (int n = 0; n < M_; ++n) {
      s[m][n] += __shfl_xor(s[m][n], 1);
      s[m][n] += __shfl_xor(s[m][n], 2);
      s[m][n] += __shfl_xor(s[m][n], 4);
    }

  float adj[M_][M_], rs[M_];
#pragma unroll
  for (int m = 0; m < M_; ++m) {
    float r = 0.f;
#pragma unroll
    for (int n = 0; n < M_; ++n) {
      float a = s[m][n] - s[n][m];
      float e = __builtin_exp2f(a * -4.328085123f);  // exp(-3a)
      float v = __builtin_amdgcn_rcpf(1.f + e);
      if (m == n) v += 1.f;
      adj[m][n] = v;
      r += v;
    }
    rs[m] = r;
  }

  const bool isb = flag[0] != 0;
  for (int k = j; k < 25; k += 8) {
    int m = k / 5, n = k - m * 5;
    float v = adj[m][n] * __builtin_amdgcn_rcpf(rs[m]);
    size_t o = ((size_t)((b * M_ + m) * M_ + n)) * HW_ + px;
    if (isb) ((__hip_bfloat16*)out)[o] = __float2bfloat16(v);
    else     ((float*)out)[o] = v;
  }
}

// ---------------- launch ----------------
extern "C" void kernel_launch(void* const* d_in, const int* in_sizes, int n_in,
                              void* d_out, int out_size, void* d_ws, size_t ws_size,
                              hipStream_t stream) {
  const void* pts = d_in[0];
  const void* W1  = d_in[1];
  const void* b1  = d_in[2];
  const void* W2  = d_in[3];
  const void* b2  = d_in[4];

  char* ws = (char*)d_ws;
  int* flag = (int*)ws;
  _Float16* xin = (_Float16*)(ws + OFF_XIN);
  _Float16* wl1 = (_Float16*)(ws + OFF_WL1);
  _Float16* wl2 = (_Float16*)(ws + OFF_WL2);
  _Float16* n1  = (_Float16*)(ws + OFF_N1);
  _Float16* n2  = (_Float16*)(ws + OFF_N2);

  sniff_kernel<<<dim3(1), dim3(64), 0, stream>>>((const unsigned short*)pts, flag);
  prep_kernel<<<dim3(4, H_, NIMG_), dim3(256), 0, stream>>>(pts, xin, flag);
  wprep_kernel<<<dim3(175, 2), dim3(256), 0, stream>>>(W1, W2, wl1, wl2, xin, flag);
  conv_fused<<<dim3(256), dim3(512), 0, stream>>>(xin, wl1, wl2, b1, b2, flag, n1, n2);
  pairwise_kernel<<<dim3(B_ * HW_ * 8 / 256), dim3(256), 0, stream>>>(n1, n2, d_out, flag);
}